// Round 1
// baseline (2504.837 us; speedup 1.0000x reference)
//
#include <hip/hip_runtime.h>
#include <math.h>

#define TT 20
#define HH 10
#define OO 3
#define MM 100
#define DD 292
#define NPB 4    // f32 fallback: nodes per block
#define NB 16    // mfma path: nodes per block
#define XP 344   // LDS row pitch (bf16 elems) for x hi/lo  (320 K-pad + bank spread)
#define MP 136   // LDS row pitch (bf16 elems) for mem      (128 K-pad + bank spread)

typedef __attribute__((ext_vector_type(4))) float f32x4;
typedef __attribute__((ext_vector_type(8))) short s16x8;
typedef __attribute__((ext_vector_type(4))) short s16x4;

__device__ __forceinline__ float b2f(unsigned short v){ return __uint_as_float(((unsigned)v)<<16); }
__device__ __forceinline__ float blo(unsigned u){ return __uint_as_float(u<<16); }
__device__ __forceinline__ float bhi(unsigned u){ return __uint_as_float(u & 0xffff0000u); }
__device__ __forceinline__ unsigned short f2b(float f){
    unsigned u=__float_as_uint(f); u += 0x7fffu + ((u>>16)&1u); return (unsigned short)(u>>16);
}

template<bool F32>
__device__ __forceinline__ float ldv(const unsigned short* p, size_t i){
    return F32 ? ((const float*)p)[i] : b2f(p[i]);
}

// Detect input dtype (bf16 vs f32) from bit patterns of `memory`, and n_id width.
__global__ void tgn_detect(const unsigned short* __restrict__ mem,
                           const int* __restrict__ nid, int* __restrict__ flags){
    int ln = threadIdx.x; // 64 threads
    unsigned short s = mem[2*ln];
    int e = (s>>7)&0xFF;
    unsigned long long bm = __ballot(e>=100 && e<=140);
    if (ln==0){
        flags[0] = (__popcll(bm) >= 24) ? 0 : 1;   // 0 = bf16, 1 = f32
        flags[1] = (nid[1]==0) ? 1 : 0;            // 1 = int64 n_id
    }
}

// ---------------- MFMA path (bf16 inputs — the real path) ----------------
// 16 nodes/block, 4 waves. GRU matvecs as 16x16x32 bf16 MFMA GEMM:
//   A = x[16 nodes][K] (LDS, hi/lo bf16 split), B = W[jo][k] fragments read
//   straight from global (8 contiguous k per lane == native B-frag layout).
// Gate-aligned col-tiles: 7 tiles of 16 cover jo=0..99; r/z/n accumulated
// in separate regs for the same (node,jo) -> in-register gate combine.
__global__ __launch_bounds__(256) void tgn_mfma(
    const int* __restrict__ n_id,
    const unsigned short* __restrict__ mem,
    const unsigned short* __restrict__ msg,
    const unsigned short* __restrict__ w1,
    const unsigned short* __restrict__ b1,
    const unsigned short* __restrict__ w2,
    const unsigned short* __restrict__ b2,
    const unsigned short* __restrict__ g3,
    const unsigned short* __restrict__ bb3,
    const unsigned short* __restrict__ lng,
    const unsigned short* __restrict__ lnb,
    const unsigned short* __restrict__ wih,
    const unsigned short* __restrict__ whh,
    unsigned short* __restrict__ out,
    const int* __restrict__ flags)
{
    if (flags[0] != 0) return;               // f32 inputs: handled by fallback
    const bool is64 = (flags[1] != 0);

    __shared__ float w1s[HH*TT], w2s[OO*HH];
    __shared__ float b1s[HH], b2s[OO], g3s[OO], b3s[OO];
    __shared__ float lngs[DD], lnbs[DD];
    __shared__ int   sgn[NB];
    __shared__ float xsf[NB][DD];            // f32 concat row (pre-LN)
    __shared__ unsigned short xh[NB][XP];    // bf16 hi of LN'd x, k in [0,320) valid
    __shared__ unsigned short xl[NB][XP];    // bf16 lo residual
    __shared__ unsigned short msb[NB][MP];   // raw bf16 mem,    k in [0,128) valid

    const int tid = threadIdx.x;
    for (int i=tid;i<HH*TT;i+=256) w1s[i]=b2f(w1[i]);
    for (int i=tid;i<OO*HH;i+=256) w2s[i]=b2f(w2[i]);
    if (tid<HH) b1s[tid]=b2f(b1[tid]);
    if (tid<OO){ b2s[tid]=b2f(b2[tid]); g3s[tid]=b2f(g3[tid]); b3s[tid]=b2f(bb3[tid]); }
    for (int i=tid;i<DD;i+=256){ lngs[i]=b2f(lng[i]); lnbs[i]=b2f(lnb[i]); }
    if (tid<NB){
        int gp = blockIdx.x*NB + tid;
        sgn[tid] = is64 ? (int)((const long long*)n_id)[gp] : n_id[gp];
    }
    // zero the K-padding so tail MFMAs multiply by 0
    for (int i=tid;i<NB*(320-DD);i+=256){ int r=i/(320-DD), c=DD+(i-r*(320-DD)); xh[r][c]=0; xl[r][c]=0; }
    for (int i=tid;i<NB*(128-MM);i+=256){ int r=i/(128-MM), c=MM+(i-r*(128-MM)); msb[r][c]=0; }
    __syncthreads();

    // ---- Phase A: FeedForward(20->10->3, exact gelu) + LN(3) on 1024 rows ----
    #pragma unroll
    for (int it=0; it<4; ++it){
        int rg = tid + 256*it;               // 0..1023
        int nd = rg>>6, rw = rg&63;
        const uint2* mp = (const uint2*)(msg + (size_t)sgn[nd]*(64*TT) + rw*TT);
        float mv[TT];
        #pragma unroll
        for (int i=0;i<5;++i){ uint2 qq=mp[i]; mv[4*i]=blo(qq.x); mv[4*i+1]=bhi(qq.x); mv[4*i+2]=blo(qq.y); mv[4*i+3]=bhi(qq.y); }
        float h[HH];
        #pragma unroll
        for (int j=0;j<HH;++j){
            float a=b1s[j];
            #pragma unroll
            for (int t=0;t<TT;++t) a += mv[t]*w1s[j*TT+t];
            h[j] = 0.5f*a*(1.0f+erff(a*0.70710678118654752f));
        }
        float y[OO];
        #pragma unroll
        for (int o=0;o<OO;++o){
            float a=b2s[o];
            #pragma unroll
            for (int j=0;j<HH;++j) a += h[j]*w2s[o*HH+j];
            y[o]=a;
        }
        float mu=(y[0]+y[1]+y[2])*(1.0f/3.0f);
        float d0=y[0]-mu, d1=y[1]-mu, d2=y[2]-mu;
        float rs=rsqrtf((d0*d0+d1*d1+d2*d2)*(1.0f/3.0f)+1e-5f);
        xsf[nd][MM+3*rw+0]=d0*rs*g3s[0]+b3s[0];
        xsf[nd][MM+3*rw+1]=d1*rs*g3s[1]+b3s[1];
        xsf[nd][MM+3*rw+2]=d2*rs*g3s[2]+b3s[2];
    }
    // mem gather -> msb (raw bf16) and xsf[0..99] (f32)
    for (int i=tid;i<NB*MM;i+=256){
        int nd=i/MM, c=i-nd*MM;
        unsigned short v = mem[(size_t)sgn[nd]*MM + c];
        msb[nd][c]=v;
        xsf[nd][c]=b2f(v);
    }
    __syncthreads();

    // ---- Phase B: LN(292) per node, then bf16 hi/lo split into xh/xl ----
    const int wv=tid>>6, ln=tid&63;
    #pragma unroll
    for (int nn=0;nn<4;++nn){
        int nd=wv*4+nn;
        float s=0.f, ss=0.f;
        for (int i=ln;i<DD;i+=64){ float v=xsf[nd][i]; s+=v; ss+=v*v; }
        #pragma unroll
        for (int off=32;off>=1;off>>=1){ s+=__shfl_xor(s,off); ss+=__shfl_xor(ss,off); }
        float mu=s*(1.0f/DD);
        float var=ss*(1.0f/DD)-mu*mu;
        float rs=rsqrtf(var+1e-5f);
        for (int i=ln;i<DD;i+=64){
            float v=(xsf[nd][i]-mu)*rs*lngs[i]+lnbs[i];
            unsigned short hb=f2b(v);
            xh[nd][i]=hb;
            xl[nd][i]=f2b(v-b2f(hb));
        }
    }
    __syncthreads();

    // ---- Phase C: GRU via MFMA ----
    // Lane roles: q = l&15 -> A-row (node) for A-frags AND B-col (jo) for B-frags;
    //             g = l>>4 -> k-group. C/D: node=(l>>4)*4+reg, jo=tile*16+(l&15).
    const int g=ln>>4, q=ln&15;
    const f32x4 z4={0.f,0.f,0.f,0.f};
    for (int tt=wv; tt<7; tt+=4){
        const int jo  = tt*16+q;
        const int joc = (jo < MM) ? jo : (MM-1);     // clamped rows never stored
        f32x4 air=z4, aiz=z4, ain=z4;                // gi accumulators (r,z,n)
        f32x4 ahr=z4, ahz=z4, ahn=z4;                // gh accumulators
        const unsigned short* wr  = wih + (size_t)joc*DD;
        const unsigned short* wzp = wih + (size_t)(joc+MM)*DD;
        const unsigned short* wnp = wih + (size_t)(joc+2*MM)*DD;
        #pragma unroll
        for (int kc=0;kc<9;++kc){                    // k = 0..287 (full chunks)
            const int k0 = kc*32 + g*8;
            s16x8 ah = *(const s16x8*)&xh[q][k0];
            s16x8 al = *(const s16x8*)&xl[q][k0];
            s16x4 r0=*(const s16x4*)(wr +k0), r1=*(const s16x4*)(wr +k0+4);
            s16x4 z0=*(const s16x4*)(wzp+k0), z1=*(const s16x4*)(wzp+k0+4);
            s16x4 n0=*(const s16x4*)(wnp+k0), n1=*(const s16x4*)(wnp+k0+4);
            s16x8 bR=__builtin_shufflevector(r0,r1,0,1,2,3,4,5,6,7);
            s16x8 bZ=__builtin_shufflevector(z0,z1,0,1,2,3,4,5,6,7);
            s16x8 bN=__builtin_shufflevector(n0,n1,0,1,2,3,4,5,6,7);
            air=__builtin_amdgcn_mfma_f32_16x16x32_bf16(ah,bR,air,0,0,0);
            air=__builtin_amdgcn_mfma_f32_16x16x32_bf16(al,bR,air,0,0,0);
            aiz=__builtin_amdgcn_mfma_f32_16x16x32_bf16(ah,bZ,aiz,0,0,0);
            aiz=__builtin_amdgcn_mfma_f32_16x16x32_bf16(al,bZ,aiz,0,0,0);
            ain=__builtin_amdgcn_mfma_f32_16x16x32_bf16(ah,bN,ain,0,0,0);
            ain=__builtin_amdgcn_mfma_f32_16x16x32_bf16(al,bN,ain,0,0,0);
        }
        {   // gi K-tail: only k=288..291 real; xh/xl zero beyond 292
            const int k0 = 288 + g*8;
            s16x8 ah = *(const s16x8*)&xh[q][k0];
            s16x8 al = *(const s16x8*)&xl[q][k0];
            s16x4 zv={0,0,0,0};
            s16x4 r0=*(const s16x4*)(wr +288);       // in-row, in-bounds for all lanes
            s16x4 z0=*(const s16x4*)(wzp+288);
            s16x4 n0=*(const s16x4*)(wnp+288);
            if (g){ r0=zv; z0=zv; n0=zv; }
            s16x8 bR=__builtin_shufflevector(r0,zv,0,1,2,3,4,5,6,7);
            s16x8 bZ=__builtin_shufflevector(z0,zv,0,1,2,3,4,5,6,7);
            s16x8 bN=__builtin_shufflevector(n0,zv,0,1,2,3,4,5,6,7);
            air=__builtin_amdgcn_mfma_f32_16x16x32_bf16(ah,bR,air,0,0,0);
            air=__builtin_amdgcn_mfma_f32_16x16x32_bf16(al,bR,air,0,0,0);
            aiz=__builtin_amdgcn_mfma_f32_16x16x32_bf16(ah,bZ,aiz,0,0,0);
            aiz=__builtin_amdgcn_mfma_f32_16x16x32_bf16(al,bZ,aiz,0,0,0);
            ain=__builtin_amdgcn_mfma_f32_16x16x32_bf16(ah,bN,ain,0,0,0);
            ain=__builtin_amdgcn_mfma_f32_16x16x32_bf16(al,bN,ain,0,0,0);
        }
        // gh: mem (exact bf16) x whh, K=100 -> 3 full chunks + tail
        const unsigned short* vr = whh + (size_t)joc*MM;
        const unsigned short* vz = whh + (size_t)(joc+MM)*MM;
        const unsigned short* vn = whh + (size_t)(joc+2*MM)*MM;
        #pragma unroll
        for (int kc=0;kc<3;++kc){                    // k = 0..95
            const int k0 = kc*32 + g*8;
            s16x8 am = *(const s16x8*)&msb[q][k0];
            s16x4 r0=*(const s16x4*)(vr+k0), r1=*(const s16x4*)(vr+k0+4);
            s16x4 z0=*(const s16x4*)(vz+k0), z1=*(const s16x4*)(vz+k0+4);
            s16x4 n0=*(const s16x4*)(vn+k0), n1=*(const s16x4*)(vn+k0+4);
            s16x8 bR=__builtin_shufflevector(r0,r1,0,1,2,3,4,5,6,7);
            s16x8 bZ=__builtin_shufflevector(z0,z1,0,1,2,3,4,5,6,7);
            s16x8 bN=__builtin_shufflevector(n0,n1,0,1,2,3,4,5,6,7);
            ahr=__builtin_amdgcn_mfma_f32_16x16x32_bf16(am,bR,ahr,0,0,0);
            ahz=__builtin_amdgcn_mfma_f32_16x16x32_bf16(am,bZ,ahz,0,0,0);
            ahn=__builtin_amdgcn_mfma_f32_16x16x32_bf16(am,bN,ahn,0,0,0);
        }
        {   // gh K-tail: k=96..99 real; msb zero beyond 100
            const int k0 = 96 + g*8;
            s16x8 am = *(const s16x8*)&msb[q][k0];
            s16x4 zv={0,0,0,0};
            s16x4 r0=*(const s16x4*)(vr+96);
            s16x4 z0=*(const s16x4*)(vz+96);
            s16x4 n0=*(const s16x4*)(vn+96);
            if (g){ r0=zv; z0=zv; n0=zv; }
            s16x8 bR=__builtin_shufflevector(r0,zv,0,1,2,3,4,5,6,7);
            s16x8 bZ=__builtin_shufflevector(z0,zv,0,1,2,3,4,5,6,7);
            s16x8 bN=__builtin_shufflevector(n0,zv,0,1,2,3,4,5,6,7);
            ahr=__builtin_amdgcn_mfma_f32_16x16x32_bf16(am,bR,ahr,0,0,0);
            ahz=__builtin_amdgcn_mfma_f32_16x16x32_bf16(am,bZ,ahz,0,0,0);
            ahn=__builtin_amdgcn_mfma_f32_16x16x32_bf16(am,bN,ahn,0,0,0);
        }
        // in-register gate combine + store (C/D: node=(g*4+reg), col=jo)
        if (jo < MM){
            const size_t ob = (size_t)blockIdx.x*NB*MM;
            #pragma unroll
            for (int rr2=0; rr2<4; ++rr2){
                int m = g*4 + rr2;
                float rgate = 1.f/(1.f+expf(-(air[rr2]+ahr[rr2])));
                float zgate = 1.f/(1.f+expf(-(aiz[rr2]+ahz[rr2])));
                float ngate = tanhf(ain[rr2] + rgate*ahn[rr2]);
                float hp = b2f(msb[m][jo]);
                out[ob + (size_t)m*MM + jo] = f2b((1.f-zgate)*ngate + zgate*hp);
            }
        }
    }
}

// ---------------- f32 fallback (unchanged proven path) ----------------
template<bool F32>
__global__ __launch_bounds__(256) void tgn_main(
    const int* __restrict__ n_id,
    const unsigned short* __restrict__ mem,
    const unsigned short* __restrict__ msg,
    const unsigned short* __restrict__ w1,
    const unsigned short* __restrict__ b1,
    const unsigned short* __restrict__ w2,
    const unsigned short* __restrict__ b2,
    const unsigned short* __restrict__ g3,
    const unsigned short* __restrict__ bb3,
    const unsigned short* __restrict__ lng,
    const unsigned short* __restrict__ lnb,
    const unsigned short* __restrict__ wih,
    const unsigned short* __restrict__ whh,
    void* __restrict__ outv,
    const int* __restrict__ flags)
{
    if (flags[0] != (F32 ? 1 : 0)) return;
    const bool is64 = (flags[1] != 0);

    __shared__ float w1s[HH*TT], w2s[OO*HH];
    __shared__ float b1s[HH], b2s[OO], g3s[OO], b3s[OO];
    __shared__ float lngs[DD], lnbs[DD];
    __shared__ float xs[NPB][DD], ms[NPB][MM];

    const int tid = threadIdx.x;
    for (int i=tid;i<HH*TT;i+=256) w1s[i]=ldv<F32>(w1,i);
    for (int i=tid;i<OO*HH;i+=256) w2s[i]=ldv<F32>(w2,i);
    if (tid<HH) b1s[tid]=ldv<F32>(b1,tid);
    if (tid<OO){ b2s[tid]=ldv<F32>(b2,tid); g3s[tid]=ldv<F32>(g3,tid); b3s[tid]=ldv<F32>(bb3,tid); }
    for (int i=tid;i<DD;i+=256){ lngs[i]=ldv<F32>(lng,i); lnbs[i]=ldv<F32>(lnb,i); }
    __syncthreads();

    const int wv = tid>>6, ln = tid&63;
    const int gidx = blockIdx.x*NPB + wv;
    const int gn = is64 ? (int)((const long long*)n_id)[gidx] : n_id[gidx];

    float mv[TT];
    if (F32){
        const float4* mp = (const float4*)((const float*)msg + (size_t)gn*(64*TT) + ln*TT);
        #pragma unroll
        for (int i=0;i<5;++i){ float4 q=mp[i]; mv[4*i]=q.x; mv[4*i+1]=q.y; mv[4*i+2]=q.z; mv[4*i+3]=q.w; }
    } else {
        const uint2* mp = (const uint2*)(msg + (size_t)gn*(64*TT) + ln*TT);
        #pragma unroll
        for (int i=0;i<5;++i){ uint2 q=mp[i]; mv[4*i]=blo(q.x); mv[4*i+1]=bhi(q.x); mv[4*i+2]=blo(q.y); mv[4*i+3]=bhi(q.y); }
    }
    {
        float h[HH];
        #pragma unroll
        for (int j=0;j<HH;++j){
            float a=b1s[j];
            #pragma unroll
            for (int t=0;t<TT;++t) a += mv[t]*w1s[j*TT+t];
            h[j] = 0.5f*a*(1.0f+erff(a*0.70710678118654752f));
        }
        float y[OO];
        #pragma unroll
        for (int o=0;o<OO;++o){
            float a=b2s[o];
            #pragma unroll
            for (int j=0;j<HH;++j) a += h[j]*w2s[o*HH+j];
            y[o]=a;
        }
        float mu=(y[0]+y[1]+y[2])*(1.0f/3.0f);
        float d0=y[0]-mu, d1=y[1]-mu, d2=y[2]-mu;
        float rs=rsqrtf((d0*d0+d1*d1+d2*d2)*(1.0f/3.0f)+1e-5f);
        xs[wv][MM+3*ln+0]=d0*rs*g3s[0]+b3s[0];
        xs[wv][MM+3*ln+1]=d1*rs*g3s[1]+b3s[1];
        xs[wv][MM+3*ln+2]=d2*rs*g3s[2]+b3s[2];
    }
    for (int i=ln;i<MM;i+=64){
        float v=ldv<F32>(mem,(size_t)gn*MM+i);
        ms[wv][i]=v; xs[wv][i]=v;
    }
    __syncthreads();

    {
        float s=0.f, ss=0.f;
        for (int i=ln;i<DD;i+=64){ float v=xs[wv][i]; s+=v; ss+=v*v; }
        #pragma unroll
        for (int off=32;off>=1;off>>=1){ s+=__shfl_xor(s,off); ss+=__shfl_xor(ss,off); }
        float mu=s*(1.0f/DD);
        float var=ss*(1.0f/DD)-mu*mu;
        float rs=rsqrtf(var+1e-5f);
        for (int i=ln;i<DD;i+=64) xs[wv][i]=(xs[wv][i]-mu)*rs*lngs[i]+lnbs[i];
    }
    __syncthreads();

    for (int jo=ln; jo<MM; jo+=64){
        float ar=0.f,az=0.f,an=0.f;
        if (F32){
            const float4* wr=(const float4*)((const float*)wih + (size_t)jo*DD);
            const float4* wz=(const float4*)((const float*)wih + (size_t)(jo+100)*DD);
            const float4* wn=(const float4*)((const float*)wih + (size_t)(jo+200)*DD);
            for (int c=0;c<DD/4;++c){
                float x0=xs[wv][4*c], x1=xs[wv][4*c+1], x2=xs[wv][4*c+2], x3=xs[wv][4*c+3];
                float4 qr=wr[c], qz=wz[c], qn=wn[c];
                ar += x0*qr.x+x1*qr.y+x2*qr.z+x3*qr.w;
                az += x0*qz.x+x1*qz.y+x2*qz.z+x3*qz.w;
                an += x0*qn.x+x1*qn.y+x2*qn.z+x3*qn.w;
            }
        } else {
            const uint2* wr=(const uint2*)(wih + (size_t)jo*DD);
            const uint2* wz=(const uint2*)(wih + (size_t)(jo+100)*DD);
            const uint2* wn=(const uint2*)(wih + (size_t)(jo+200)*DD);
            for (int c=0;c<DD/4;++c){
                float x0=xs[wv][4*c], x1=xs[wv][4*c+1], x2=xs[wv][4*c+2], x3=xs[wv][4*c+3];
                uint2 qr=wr[c], qz=wz[c], qn=wn[c];
                ar += x0*blo(qr.x)+x1*bhi(qr.x)+x2*blo(qr.y)+x3*bhi(qr.y);
                az += x0*blo(qz.x)+x1*bhi(qz.x)+x2*blo(qz.y)+x3*bhi(qz.y);
                an += x0*blo(qn.x)+x1*bhi(qn.x)+x2*blo(qn.y)+x3*bhi(qn.y);
            }
        }
        float br=0.f,bz=0.f,bn=0.f;
        if (F32){
            const float4* vr=(const float4*)((const float*)whh + (size_t)jo*MM);
            const float4* vz=(const float4*)((const float*)whh + (size_t)(jo+100)*MM);
            const float4* vn=(const float4*)((const float*)whh + (size_t)(jo+200)*MM);
            for (int c=0;c<MM/4;++c){
                float h0=ms[wv][4*c],h1=ms[wv][4*c+1],h2=ms[wv][4*c+2],h3=ms[wv][4*c+3];
                float4 qr=vr[c],qz=vz[c],qn=vn[c];
                br += h0*qr.x+h1*qr.y+h2*qr.z+h3*qr.w;
                bz += h0*qz.x+h1*qz.y+h2*qz.z+h3*qz.w;
                bn += h0*qn.x+h1*qn.y+h2*qn.z+h3*qn.w;
            }
        } else {
            const uint2* vr=(const uint2*)(whh + (size_t)jo*MM);
            const uint2* vz=(const uint2*)(whh + (size_t)(jo+100)*MM);
            const uint2* vn=(const uint2*)(whh + (size_t)(jo+200)*MM);
            for (int c=0;c<MM/4;++c){
                float h0=ms[wv][4*c],h1=ms[wv][4*c+1],h2=ms[wv][4*c+2],h3=ms[wv][4*c+3];
                uint2 qr=vr[c],qz=vz[c],qn=vn[c];
                br += h0*blo(qr.x)+h1*bhi(qr.x)+h2*blo(qr.y)+h3*bhi(qr.y);
                bz += h0*blo(qz.x)+h1*bhi(qz.x)+h2*blo(qz.y)+h3*bhi(qz.y);
                bn += h0*blo(qn.x)+h1*bhi(qn.x)+h2*blo(qn.y)+h3*bhi(qn.y);
            }
        }
        float rg = 1.0f/(1.0f+expf(-(ar+br)));
        float zg = 1.0f/(1.0f+expf(-(az+bz)));
        float ng = tanhf(an + rg*bn);
        float hp = ms[wv][jo];
        float o  = (1.0f-zg)*ng + zg*hp;
        size_t oi = (size_t)gidx*MM + jo;
        if (F32) ((float*)outv)[oi]=o; else ((unsigned short*)outv)[oi]=f2b(o);
    }
}

extern "C" void kernel_launch(void* const* d_in, const int* in_sizes, int n_in,
                              void* d_out, int out_size, void* d_ws, size_t ws_size,
                              hipStream_t stream) {
    (void)in_sizes; (void)n_in; (void)out_size; (void)ws_size;
    const int* n_id           = (const int*)d_in[0];
    const unsigned short* mem = (const unsigned short*)d_in[1];
    const unsigned short* msg = (const unsigned short*)d_in[2];
    const unsigned short* w1  = (const unsigned short*)d_in[3];
    const unsigned short* b1  = (const unsigned short*)d_in[4];
    const unsigned short* w2  = (const unsigned short*)d_in[5];
    const unsigned short* b2  = (const unsigned short*)d_in[6];
    const unsigned short* g3  = (const unsigned short*)d_in[7];
    const unsigned short* bb3 = (const unsigned short*)d_in[8];
    const unsigned short* lng = (const unsigned short*)d_in[9];
    const unsigned short* lnb = (const unsigned short*)d_in[10];
    const unsigned short* wih = (const unsigned short*)d_in[11];
    const unsigned short* whh = (const unsigned short*)d_in[12];
    int* flags = (int*)d_ws;

    tgn_detect<<<1, 64, 0, stream>>>(mem, n_id, flags);

    // bf16 path: 16 nodes/block, MFMA GRU
    tgn_mfma<<<dim3(50000 / NB), dim3(256), 0, stream>>>(
        n_id, mem, msg, w1, b1, w2, b2, g3, bb3, lng, lnb, wih, whh,
        (unsigned short*)d_out, flags);

    // f32 fallback: proven scalar path
    tgn_main<true><<<dim3(50000 / NPB), dim3(256), 0, stream>>>(
        n_id, mem, msg, w1, b1, w2, b2, g3, bb3, lng, lnb, wih, whh, d_out, flags);
}